// Round 9
// baseline (223.428 us; speedup 1.0000x reference)
//
#include <hip/hip_runtime.h>
#include <math.h>

#define NN 50000
#define EE 600000
#define DD 128
#define KAPPA_C 0.95f
#define EPS_C 1e-5f
#define SCAN_BLK 1024
#define NB_SCAN ((NN + SCAN_BLK - 1) / SCAN_BLK)   // 49
#define NSLICE 8
#define SLICE_N ((NN + NSLICE - 1) / NSLICE)       // 6250
#define FCHUNK 192

typedef short s16x8 __attribute__((ext_vector_type(8)));   // 8 bf16 (4 VGPRs)
typedef float f32x4 __attribute__((ext_vector_type(4)));

__device__ __forceinline__ unsigned short f2bf(float f) {
    union { float f; unsigned int u; } v;
    v.f = f;
    unsigned int r = v.u + 0x7fffu + ((v.u >> 16) & 1u);
    return (unsigned short)(r >> 16);
}
__device__ __forceinline__ float bf2f(unsigned short b) {
    union { unsigned int u; float f; } v;
    v.u = ((unsigned int)b) << 16;
    return v.f;
}

// ---------------- W = Fm^T Fm, plus sum of squares ----------------
__global__ __launch_bounds__(128) void wmat_kernel(const float* __restrict__ Fm,
                                                   float* __restrict__ W,
                                                   float* __restrict__ ssq) {
    const int i = blockIdx.x;
    const int j = threadIdx.x;
    float acc = 0.f;
    #pragma unroll 8
    for (int k = 0; k < 128; ++k)
        acc += Fm[k * 128 + i] * Fm[k * 128 + j];
    W[i * 128 + j] = acc;
    __shared__ float red[128];
    red[j] = acc * acc;
    __syncthreads();
    for (int o = 64; o > 0; o >>= 1) {
        if (j < o) red[j] += red[j + o];
        __syncthreads();
    }
    if (j == 0) atomicAdd(ssq, red[0]);
}

// scale Wmat by KAPPA * (norm>1 ? 1/(norm+eps) : 1), emit transposed split-bf16
__global__ __launch_bounds__(256) void wsplit_kernel(const float* __restrict__ Wmat,
                                                     const float* __restrict__ ssq,
                                                     unsigned short* __restrict__ Mth,
                                                     unsigned short* __restrict__ Mtl) {
    int id = blockIdx.x * 256 + threadIdx.x;
    float n = sqrtf(*ssq);
    float s = ((n > 1.0f) ? 1.0f / (n + EPS_C) : 1.0f) * KAPPA_C;
    float v = Wmat[id] * s;
    int k = id >> 7, c = id & 127;
    unsigned short h = f2bf(v);
    Mth[c * 128 + k] = h;
    Mtl[c * 128 + k] = f2bf(v - bf2f(h));
}

__global__ __launch_bounds__(256) void convm2_kernel(const float* __restrict__ W1,
                                                     const float* __restrict__ W2,
                                                     unsigned short* __restrict__ W1th,
                                                     unsigned short* __restrict__ W1tl,
                                                     unsigned short* __restrict__ W2th,
                                                     unsigned short* __restrict__ W2tl) {
    int b = blockIdx.x;
    const float* M = (b < 64) ? W1 : W2;
    unsigned short* H = (b < 64) ? W1th : W2th;
    unsigned short* L = (b < 64) ? W1tl : W2tl;
    int id = (b & 63) * 256 + threadIdx.x;
    float v = M[id];
    int k = id >> 7, c = id & 127;
    unsigned short h = f2bf(v);
    H[c * 128 + k] = h;
    L[c * 128 + k] = f2bf(v - bf2f(h));
}

// ---------------- CSR build (XCD-sliced) ----------------
__global__ __launch_bounds__(256) void hist_kernel(const int* __restrict__ dst,
                                                   int* __restrict__ counts) {
    const int slice = blockIdx.x & (NSLICE - 1);
    const int lo = slice * SLICE_N;
    const int hi = lo + SLICE_N;
    const int chunk = blockIdx.x >> 3;
    const int per = (EE + FCHUNK - 1) / FCHUNK;
    const int e0 = chunk * per;
    int e1 = e0 + per; if (e1 > EE) e1 = EE;
    for (int e = e0 + threadIdx.x; e < e1; e += 256) {
        int d = __builtin_nontemporal_load(&dst[e]);
        if (d >= lo && d < hi) atomicAdd(&counts[d], 1);
    }
}

__global__ __launch_bounds__(SCAN_BLK) void scan_blocks(const int* __restrict__ counts,
                                                        int* __restrict__ rs,
                                                        int* __restrict__ bsum) {
    __shared__ int sd[SCAN_BLK];
    int tid = threadIdx.x;
    int gid = blockIdx.x * SCAN_BLK + tid;
    int v = (gid < NN) ? counts[gid] : 0;
    sd[tid] = v;
    __syncthreads();
    for (int o = 1; o < SCAN_BLK; o <<= 1) {
        int t = (tid >= o) ? sd[tid - o] : 0;
        __syncthreads();
        sd[tid] += t;
        __syncthreads();
    }
    if (gid < NN) rs[gid] = sd[tid] - v;
    if (tid == SCAN_BLK - 1) bsum[blockIdx.x] = sd[tid];
}

__global__ __launch_bounds__(SCAN_BLK) void scan_add(int* __restrict__ rs,
                                                     const int* __restrict__ bsum) {
    __shared__ int pre;
    if (threadIdx.x == 0) {
        int run = 0;
        for (int i = 0; i < (int)blockIdx.x; ++i) run += bsum[i];
        pre = run;
    }
    __syncthreads();
    int gid = blockIdx.x * SCAN_BLK + threadIdx.x;
    if (gid < NN) rs[gid] += pre;
    if (gid == NN - 1) rs[NN] = EE;
}

__global__ __launch_bounds__(256) void fill_kernel(const int* __restrict__ src,
                                                   const int* __restrict__ dst,
                                                   const float* __restrict__ w,
                                                   const int* __restrict__ rs,
                                                   int* __restrict__ cursor,
                                                   int2* __restrict__ csr) {
    const int slice = blockIdx.x & (NSLICE - 1);
    const int lo = slice * SLICE_N;
    const int hi = lo + SLICE_N;
    const int chunk = blockIdx.x >> 3;
    const int per = (EE + FCHUNK - 1) / FCHUNK;
    const int e0 = chunk * per;
    int e1 = e0 + per; if (e1 > EE) e1 = EE;
    for (int e = e0 + threadIdx.x; e < e1; e += 256) {
        int d = __builtin_nontemporal_load(&dst[e]);
        if (d >= lo && d < hi) {
            int pos = atomicAdd(&cursor[d], 1);
            csr[rs[d] + pos] = make_int2(__builtin_nontemporal_load(&src[e]),
                                         __float_as_int(__builtin_nontemporal_load(&w[e])));
        }
    }
}

// ---------------- MFMA GEMM: 32-row block tile, wave tile 32x32, high-TLP ----------------
// grid = ceil(N/32); 4 waves cover the 128 output cols.
__global__ __launch_bounds__(256, 4) void gemm_mfma(const float* __restrict__ X,
                                                    const unsigned short* __restrict__ Mth,
                                                    const unsigned short* __restrict__ Mtl,
                                                    unsigned short* __restrict__ outh,
                                                    int nrows) {
    const int wave = threadIdx.x >> 6;
    const int lane = threadIdx.x & 63;
    const int row0 = blockIdx.x * 32;
    const int col0 = wave * 32;
    const int lr = lane & 15;
    const int kg = lane >> 4;

    f32x4 acc[2][2];
    #pragma unroll
    for (int m = 0; m < 2; ++m)
        #pragma unroll
        for (int n = 0; n < 2; ++n)
            acc[m][n] = (f32x4){0.f, 0.f, 0.f, 0.f};

    #pragma unroll
    for (int k0 = 0; k0 < 128; k0 += 32) {
        s16x8 a[2];
        #pragma unroll
        for (int m = 0; m < 2; ++m) {
            int r = row0 + m * 16 + lr;
            if (r >= nrows) r = nrows - 1;
            const float* xp = X + (size_t)r * 128 + k0 + kg * 8;
            float4 f0 = ((const float4*)xp)[0];
            float4 f1 = ((const float4*)xp)[1];
            union { s16x8 v; unsigned short u[8]; } cv;
            cv.u[0] = f2bf(f0.x); cv.u[1] = f2bf(f0.y); cv.u[2] = f2bf(f0.z); cv.u[3] = f2bf(f0.w);
            cv.u[4] = f2bf(f1.x); cv.u[5] = f2bf(f1.y); cv.u[6] = f2bf(f1.z); cv.u[7] = f2bf(f1.w);
            a[m] = cv.v;
        }
        #pragma unroll
        for (int n = 0; n < 2; ++n) {
            const int c = col0 + n * 16 + lr;
            s16x8 bh = *(const s16x8*)(Mth + c * 128 + k0 + kg * 8);
            s16x8 bl = *(const s16x8*)(Mtl + c * 128 + k0 + kg * 8);
            #pragma unroll
            for (int m = 0; m < 2; ++m) {
                acc[m][n] = __builtin_amdgcn_mfma_f32_16x16x32_bf16(a[m], bh, acc[m][n], 0, 0, 0);
                acc[m][n] = __builtin_amdgcn_mfma_f32_16x16x32_bf16(a[m], bl, acc[m][n], 0, 0, 0);
            }
        }
    }

    // D layout: col = lane&15, row = (lane>>4)*4 + j   [m89]
    #pragma unroll
    for (int m = 0; m < 2; ++m)
        #pragma unroll
        for (int n = 0; n < 2; ++n)
            #pragma unroll
            for (int j = 0; j < 4; ++j) {
                int r = row0 + m * 16 + kg * 4 + j;
                int c = col0 + n * 16 + lr;
                if (r < nrows)
                    outh[(size_t)r * 128 + c] = f2bf(acc[m][n][j]);
            }
}

// ---------------- dual GEMM: P = bf16( H@W2 + emb@Wm' ), 32-row tiles, high-TLP ----------------
__global__ __launch_bounds__(256, 4) void gemm_pe(const unsigned short* __restrict__ Hbf,
                                                  const float* __restrict__ emb,
                                                  const unsigned short* __restrict__ W2th,
                                                  const unsigned short* __restrict__ W2tl,
                                                  const unsigned short* __restrict__ Wmth,
                                                  const unsigned short* __restrict__ Wmtl,
                                                  unsigned short* __restrict__ P,
                                                  int nrows) {
    const int wave = threadIdx.x >> 6;
    const int lane = threadIdx.x & 63;
    const int row0 = blockIdx.x * 32;
    const int col0 = wave * 32;
    const int lr = lane & 15;
    const int kg = lane >> 4;

    f32x4 acc[2][2];
    #pragma unroll
    for (int m = 0; m < 2; ++m)
        #pragma unroll
        for (int n = 0; n < 2; ++n)
            acc[m][n] = (f32x4){0.f, 0.f, 0.f, 0.f};

    #pragma unroll
    for (int k0 = 0; k0 < 128; k0 += 32) {
        s16x8 ah[2], ae[2];
        #pragma unroll
        for (int m = 0; m < 2; ++m) {
            int r = row0 + m * 16 + lr;
            if (r >= nrows) r = nrows - 1;
            ah[m] = *(const s16x8*)(Hbf + (size_t)r * 128 + k0 + kg * 8);
            const float* xp = emb + (size_t)r * 128 + k0 + kg * 8;
            float4 f0 = ((const float4*)xp)[0];
            float4 f1 = ((const float4*)xp)[1];
            union { s16x8 v; unsigned short u[8]; } cv;
            cv.u[0] = f2bf(f0.x); cv.u[1] = f2bf(f0.y); cv.u[2] = f2bf(f0.z); cv.u[3] = f2bf(f0.w);
            cv.u[4] = f2bf(f1.x); cv.u[5] = f2bf(f1.y); cv.u[6] = f2bf(f1.z); cv.u[7] = f2bf(f1.w);
            ae[m] = cv.v;
        }
        #pragma unroll
        for (int n = 0; n < 2; ++n) {
            const int c = col0 + n * 16 + lr;
            s16x8 b2h = *(const s16x8*)(W2th + c * 128 + k0 + kg * 8);
            s16x8 b2l = *(const s16x8*)(W2tl + c * 128 + k0 + kg * 8);
            s16x8 bmh = *(const s16x8*)(Wmth + c * 128 + k0 + kg * 8);
            s16x8 bml = *(const s16x8*)(Wmtl + c * 128 + k0 + kg * 8);
            #pragma unroll
            for (int m = 0; m < 2; ++m) {
                acc[m][n] = __builtin_amdgcn_mfma_f32_16x16x32_bf16(ah[m], b2h, acc[m][n], 0, 0, 0);
                acc[m][n] = __builtin_amdgcn_mfma_f32_16x16x32_bf16(ah[m], b2l, acc[m][n], 0, 0, 0);
                acc[m][n] = __builtin_amdgcn_mfma_f32_16x16x32_bf16(ae[m], bmh, acc[m][n], 0, 0, 0);
                acc[m][n] = __builtin_amdgcn_mfma_f32_16x16x32_bf16(ae[m], bml, acc[m][n], 0, 0, 0);
            }
        }
    }

    #pragma unroll
    for (int m = 0; m < 2; ++m)
        #pragma unroll
        for (int n = 0; n < 2; ++n)
            #pragma unroll
            for (int j = 0; j < 4; ++j) {
                int r = row0 + m * 16 + kg * 4 + j;
                int c = col0 + n * 16 + lr;
                if (r < nrows)
                    P[(size_t)r * 128 + c] = f2bf(acc[m][n][j]);
            }
}

// ---------------- SpMM 1: h = bf16(relu(A @ h1 + b1)), 32 lanes/node, 4-edge unroll ----------------
__global__ __launch_bounds__(256) void spmm_relu(const unsigned short* __restrict__ h,
                                                 const int* __restrict__ rs,
                                                 const int2* __restrict__ csr,
                                                 const float* __restrict__ bias,
                                                 unsigned short* __restrict__ outh) {
    int node = blockIdx.x * 8 + (threadIdx.x >> 5);
    int lane = threadIdx.x & 31;
    if (node >= NN) return;
    int e = rs[node];
    const int re = rs[node + 1];
    float4 acc = make_float4(0.f, 0.f, 0.f, 0.f);
    for (; e + 3 < re; e += 4) {
        int2 p0 = csr[e];
        int2 p1 = csr[e + 1];
        int2 p2 = csr[e + 2];
        int2 p3 = csr[e + 3];
        ushort4 v0 = *(const ushort4*)(h + (size_t)p0.x * 128 + lane * 4);
        ushort4 v1 = *(const ushort4*)(h + (size_t)p1.x * 128 + lane * 4);
        ushort4 v2 = *(const ushort4*)(h + (size_t)p2.x * 128 + lane * 4);
        ushort4 v3 = *(const ushort4*)(h + (size_t)p3.x * 128 + lane * 4);
        float w0 = __int_as_float(p0.y), w1 = __int_as_float(p1.y);
        float w2 = __int_as_float(p2.y), w3 = __int_as_float(p3.y);
        acc.x += w0 * bf2f(v0.x) + w1 * bf2f(v1.x) + w2 * bf2f(v2.x) + w3 * bf2f(v3.x);
        acc.y += w0 * bf2f(v0.y) + w1 * bf2f(v1.y) + w2 * bf2f(v2.y) + w3 * bf2f(v3.y);
        acc.z += w0 * bf2f(v0.z) + w1 * bf2f(v1.z) + w2 * bf2f(v2.z) + w3 * bf2f(v3.z);
        acc.w += w0 * bf2f(v0.w) + w1 * bf2f(v1.w) + w2 * bf2f(v2.w) + w3 * bf2f(v3.w);
    }
    for (; e < re; ++e) {
        int2 p0 = csr[e];
        float w0 = __int_as_float(p0.y);
        ushort4 v0 = *(const ushort4*)(h + (size_t)p0.x * 128 + lane * 4);
        acc.x += w0 * bf2f(v0.x); acc.y += w0 * bf2f(v0.y);
        acc.z += w0 * bf2f(v0.z); acc.w += w0 * bf2f(v0.w);
    }
    float4 b = ((const float4*)bias)[lane];
    acc.x = fmaxf(acc.x + b.x, 0.f); acc.y = fmaxf(acc.y + b.y, 0.f);
    acc.z = fmaxf(acc.z + b.z, 0.f); acc.w = fmaxf(acc.w + b.w, 0.f);
    ushort4 o;
    o.x = f2bf(acc.x); o.y = f2bf(acc.y); o.z = f2bf(acc.z); o.w = f2bf(acc.w);
    ((ushort4*)(outh + (size_t)node * 128))[lane] = o;
}

// ---------------- final SpMM: out = A@P + b2 (f32 out), 32 lanes/node, 4-edge unroll ----------------
__global__ __launch_bounds__(256) void spmm_final(const unsigned short* __restrict__ P,
                                                  const int* __restrict__ rs,
                                                  const int2* __restrict__ csr,
                                                  const float* __restrict__ b2,
                                                  float* __restrict__ out) {
    int node = blockIdx.x * 8 + (threadIdx.x >> 5);
    int lane = threadIdx.x & 31;
    if (node >= NN) return;
    int e = rs[node];
    const int re = rs[node + 1];
    float4 acc = make_float4(0.f, 0.f, 0.f, 0.f);
    for (; e + 3 < re; e += 4) {
        int2 p0 = csr[e];
        int2 p1 = csr[e + 1];
        int2 p2 = csr[e + 2];
        int2 p3 = csr[e + 3];
        ushort4 v0 = *(const ushort4*)(P + (size_t)p0.x * 128 + lane * 4);
        ushort4 v1 = *(const ushort4*)(P + (size_t)p1.x * 128 + lane * 4);
        ushort4 v2 = *(const ushort4*)(P + (size_t)p2.x * 128 + lane * 4);
        ushort4 v3 = *(const ushort4*)(P + (size_t)p3.x * 128 + lane * 4);
        float w0 = __int_as_float(p0.y), w1 = __int_as_float(p1.y);
        float w2 = __int_as_float(p2.y), w3 = __int_as_float(p3.y);
        acc.x += w0 * bf2f(v0.x) + w1 * bf2f(v1.x) + w2 * bf2f(v2.x) + w3 * bf2f(v3.x);
        acc.y += w0 * bf2f(v0.y) + w1 * bf2f(v1.y) + w2 * bf2f(v2.y) + w3 * bf2f(v3.y);
        acc.z += w0 * bf2f(v0.z) + w1 * bf2f(v1.z) + w2 * bf2f(v2.z) + w3 * bf2f(v3.z);
        acc.w += w0 * bf2f(v0.w) + w1 * bf2f(v1.w) + w2 * bf2f(v2.w) + w3 * bf2f(v3.w);
    }
    for (; e < re; ++e) {
        int2 p0 = csr[e];
        float w0 = __int_as_float(p0.y);
        ushort4 v0 = *(const ushort4*)(P + (size_t)p0.x * 128 + lane * 4);
        acc.x += w0 * bf2f(v0.x); acc.y += w0 * bf2f(v0.y);
        acc.z += w0 * bf2f(v0.z); acc.w += w0 * bf2f(v0.w);
    }
    float4 b = ((const float4*)b2)[lane];
    float4 r;
    r.x = acc.x + b.x; r.y = acc.y + b.y; r.z = acc.z + b.z; r.w = acc.w + b.w;
    ((float4*)(out + (size_t)node * 128))[lane] = r;
}

static inline size_t align_up(size_t x, size_t a) { return (x + a - 1) / a * a; }

extern "C" void kernel_launch(void* const* d_in, const int* in_sizes, int n_in,
                              void* d_out, int out_size, void* d_ws, size_t ws_size,
                              hipStream_t stream) {
    const float* x   = (const float*)d_in[0];
    const int*   esrc = (const int*)d_in[1];
    const int*   edst = (const int*)d_in[2];
    const float* ew  = (const float*)d_in[3];
    const float* W1  = (const float*)d_in[4];
    const float* b1  = (const float*)d_in[5];
    const float* W2  = (const float*)d_in[6];
    const float* b2  = (const float*)d_in[7];
    const float* Fm  = (const float*)d_in[8];
    const float* emb = (const float*)d_in[9];
    float* out = (float*)d_out;

    char* ws = (char*)d_ws;
    size_t off = 0;
    auto alloc = [&](size_t bytes) -> void* {
        void* p = ws + off;
        off = align_up(off + bytes, 256);
        return p;
    };
    unsigned short* B1 = (unsigned short*)alloc((size_t)NN * DD * 2);   // 12.8 MB: h1, then P
    float* Wmat   = (float*)alloc(128 * 128 * 4);
    int*   counts = (int*)alloc((size_t)NN * 4);
    int*   cursor = (int*)alloc((size_t)NN * 4);
    float* ssq    = (float*)alloc(256);
    int*   rs     = (int*)alloc((size_t)(NN + 1) * 4);
    int*   bsum   = (int*)alloc(64 * 4);
    int2*  csr    = (int2*)alloc((size_t)EE * 8);                       // 4.8 MB
    unsigned short* W1th = (unsigned short*)alloc(128 * 128 * 2);
    unsigned short* W1tl = (unsigned short*)alloc(128 * 128 * 2);
    unsigned short* W2th = (unsigned short*)alloc(128 * 128 * 2);
    unsigned short* W2tl = (unsigned short*)alloc(128 * 128 * 2);
    unsigned short* Wmth = (unsigned short*)alloc(128 * 128 * 2);
    unsigned short* Wmtl = (unsigned short*)alloc(128 * 128 * 2);
    if (off > ws_size) return;

    // h (relu output, [N][128] bf16, 12.8 MB) lives in d_out's bytes;
    // dead after gemm_pe reads it, before spmm_final writes out.
    unsigned short* H = (unsigned short*)d_out;

    // zero [counts | cursor | ssq]
    size_t zero_bytes = (size_t)((char*)ssq - (char*)counts) + 256;
    hipMemsetAsync(counts, 0, zero_bytes, stream);

    // projection matrix + weight conversions (kappa folded into Wm split)
    wmat_kernel<<<128, 128, 0, stream>>>(Fm, Wmat, ssq);
    wsplit_kernel<<<64, 256, 0, stream>>>(Wmat, ssq, Wmth, Wmtl);
    convm2_kernel<<<128, 256, 0, stream>>>(W1, W2, W1th, W1tl, W2th, W2tl);

    // CSR build (XCD-sliced)
    const int sgrid = NSLICE * FCHUNK;   // 1536
    hist_kernel<<<sgrid, 256, 0, stream>>>(edst, counts);
    scan_blocks<<<NB_SCAN, SCAN_BLK, 0, stream>>>(counts, rs, bsum);
    scan_add<<<NB_SCAN, SCAN_BLK, 0, stream>>>(rs, bsum);
    fill_kernel<<<sgrid, 256, 0, stream>>>(esrc, edst, ew, rs, cursor, csr);

    const int gemm_grid = (NN + 31) / 32;     // 1563 (32-row tiles, high TLP)
    const int spmm_grid = (NN + 7) / 8;       // 6250

    // h1 = bf16(x @ W1) -> B1
    gemm_mfma<<<gemm_grid, 256, 0, stream>>>(x, W1th, W1tl, B1, NN);
    // h = bf16(relu(A @ h1 + b1)) -> H (in d_out bytes)
    spmm_relu<<<spmm_grid, 256, 0, stream>>>(B1, rs, csr, b1, H);
    // P = bf16(h @ W2 + emb @ Wm') -> B1   (dual-A GEMM; h1 dead)
    gemm_pe<<<gemm_grid, 256, 0, stream>>>(H, emb, W2th, W2tl, Wmth, Wmtl, B1, NN);
    // out = A @ P + b2  (single 256B-row gather pass)
    spmm_final<<<spmm_grid, 256, 0, stream>>>(B1, rs, csr, b2, out);
}

// Round 10
// 187.753 us; speedup vs baseline: 1.1900x; 1.1900x over previous
//
#include <hip/hip_runtime.h>
#include <math.h>

#define NN 50000
#define EE 600000
#define DD 128
#define KAPPA_C 0.95f
#define EPS_C 1e-5f
#define SCAN_BLK 1024
#define NB_SCAN ((NN + SCAN_BLK - 1) / SCAN_BLK)   // 49
#define NSLICE 8
#define SLICE_N ((NN + NSLICE - 1) / NSLICE)       // 6250
#define FCHUNK 192

typedef short s16x8 __attribute__((ext_vector_type(8)));   // 8 bf16 (4 VGPRs)
typedef float f32x4 __attribute__((ext_vector_type(4)));

__device__ __forceinline__ unsigned short f2bf(float f) {
    union { float f; unsigned int u; } v;
    v.f = f;
    unsigned int r = v.u + 0x7fffu + ((v.u >> 16) & 1u);
    return (unsigned short)(r >> 16);
}
__device__ __forceinline__ float bf2f(unsigned short b) {
    union { unsigned int u; float f; } v;
    v.u = ((unsigned int)b) << 16;
    return v.f;
}
// fragment-contiguous ("swizzled") layout for MFMA operands, element (r, k):
//   (r>>4)*2048 + (k>>3)*128 + (r&15)*8 + (k&7)   [shorts]
// => a wave's 16x32 fragment tile (lr 0..15, kg 0..3) is one contiguous 1KB block.

// ---------------- W = Fm^T Fm, plus sum of squares ----------------
__global__ __launch_bounds__(128) void wmat_kernel(const float* __restrict__ Fm,
                                                   float* __restrict__ W,
                                                   float* __restrict__ ssq) {
    const int i = blockIdx.x;
    const int j = threadIdx.x;
    float acc = 0.f;
    #pragma unroll 8
    for (int k = 0; k < 128; ++k)
        acc += Fm[k * 128 + i] * Fm[k * 128 + j];
    W[i * 128 + j] = acc;
    __shared__ float red[128];
    red[j] = acc * acc;
    __syncthreads();
    for (int o = 64; o > 0; o >>= 1) {
        if (j < o) red[j] += red[j + o];
        __syncthreads();
    }
    if (j == 0) atomicAdd(ssq, red[0]);
}

// scale Wmat by KAPPA * (norm>1 ? 1/(norm+eps) : 1), emit SWIZZLED split-bf16 (B[c][k])
__global__ __launch_bounds__(256) void wsplit_kernel(const float* __restrict__ Wmat,
                                                     const float* __restrict__ ssq,
                                                     unsigned short* __restrict__ Mth,
                                                     unsigned short* __restrict__ Mtl) {
    int id = blockIdx.x * 256 + threadIdx.x;     // id = k*128 + c
    float n = sqrtf(*ssq);
    float s = ((n > 1.0f) ? 1.0f / (n + EPS_C) : 1.0f) * KAPPA_C;
    float v = Wmat[id] * s;
    int k = id >> 7, c = id & 127;
    size_t o = (size_t)(c >> 4) * 2048 + (size_t)(k >> 3) * 128 + (c & 15) * 8 + (k & 7);
    unsigned short h = f2bf(v);
    Mth[o] = h;
    Mtl[o] = f2bf(v - bf2f(h));
}

__global__ __launch_bounds__(256) void convm2_kernel(const float* __restrict__ W1,
                                                     const float* __restrict__ W2,
                                                     unsigned short* __restrict__ W1th,
                                                     unsigned short* __restrict__ W1tl,
                                                     unsigned short* __restrict__ W2th,
                                                     unsigned short* __restrict__ W2tl) {
    int b = blockIdx.x;
    const float* M = (b < 64) ? W1 : W2;
    unsigned short* H = (b < 64) ? W1th : W2th;
    unsigned short* L = (b < 64) ? W1tl : W2tl;
    int id = (b & 63) * 256 + threadIdx.x;       // id = k*128 + c
    float v = M[id];
    int k = id >> 7, c = id & 127;
    size_t o = (size_t)(c >> 4) * 2048 + (size_t)(k >> 3) * 128 + (c & 15) * 8 + (k & 7);
    unsigned short h = f2bf(v);
    H[o] = h;
    L[o] = f2bf(v - bf2f(h));
}

// ---------------- conv: f32 row-major [N][128] -> bf16 swizzled ----------------
// one 16-row tile per block; coalesced reads, full-line swizzled writes.
__global__ __launch_bounds__(256) void conv_swz(const float* __restrict__ in,
                                                unsigned short* __restrict__ outp) {
    const int t = blockIdx.x;            // tile (16 rows)
    const int rl = threadIdx.x >> 4;     // 0..15 row within tile
    const int kq = threadIdx.x & 15;     // 0..15 k-chunk (8 elems)
    const float* xp = in + (size_t)(t * 16 + rl) * 128 + kq * 8;
    float4 f0 = ((const float4*)xp)[0];
    float4 f1 = ((const float4*)xp)[1];
    union { s16x8 v; unsigned short u[8]; } cv;
    cv.u[0] = f2bf(f0.x); cv.u[1] = f2bf(f0.y); cv.u[2] = f2bf(f0.z); cv.u[3] = f2bf(f0.w);
    cv.u[4] = f2bf(f1.x); cv.u[5] = f2bf(f1.y); cv.u[6] = f2bf(f1.z); cv.u[7] = f2bf(f1.w);
    *(s16x8*)(outp + (size_t)t * 2048 + (size_t)kq * 128 + rl * 8) = cv.v;
}

// ---------------- CSR build (XCD-sliced) ----------------
__global__ __launch_bounds__(256) void hist_kernel(const int* __restrict__ dst,
                                                   int* __restrict__ counts) {
    const int slice = blockIdx.x & (NSLICE - 1);
    const int lo = slice * SLICE_N;
    const int hi = lo + SLICE_N;
    const int chunk = blockIdx.x >> 3;
    const int per = (EE + FCHUNK - 1) / FCHUNK;
    const int e0 = chunk * per;
    int e1 = e0 + per; if (e1 > EE) e1 = EE;
    for (int e = e0 + threadIdx.x; e < e1; e += 256) {
        int d = __builtin_nontemporal_load(&dst[e]);
        if (d >= lo && d < hi) atomicAdd(&counts[d], 1);
    }
}

__global__ __launch_bounds__(SCAN_BLK) void scan_blocks(const int* __restrict__ counts,
                                                        int* __restrict__ rs,
                                                        int* __restrict__ bsum) {
    __shared__ int sd[SCAN_BLK];
    int tid = threadIdx.x;
    int gid = blockIdx.x * SCAN_BLK + tid;
    int v = (gid < NN) ? counts[gid] : 0;
    sd[tid] = v;
    __syncthreads();
    for (int o = 1; o < SCAN_BLK; o <<= 1) {
        int t = (tid >= o) ? sd[tid - o] : 0;
        __syncthreads();
        sd[tid] += t;
        __syncthreads();
    }
    if (gid < NN) rs[gid] = sd[tid] - v;
    if (tid == SCAN_BLK - 1) bsum[blockIdx.x] = sd[tid];
}

__global__ __launch_bounds__(SCAN_BLK) void scan_add(int* __restrict__ rs,
                                                     const int* __restrict__ bsum) {
    __shared__ int pre;
    if (threadIdx.x == 0) {
        int run = 0;
        for (int i = 0; i < (int)blockIdx.x; ++i) run += bsum[i];
        pre = run;
    }
    __syncthreads();
    int gid = blockIdx.x * SCAN_BLK + threadIdx.x;
    if (gid < NN) rs[gid] += pre;
    if (gid == NN - 1) rs[NN] = EE;
}

__global__ __launch_bounds__(256) void fill_kernel(const int* __restrict__ src,
                                                   const int* __restrict__ dst,
                                                   const float* __restrict__ w,
                                                   const int* __restrict__ rs,
                                                   int* __restrict__ cursor,
                                                   int2* __restrict__ csr) {
    const int slice = blockIdx.x & (NSLICE - 1);
    const int lo = slice * SLICE_N;
    const int hi = lo + SLICE_N;
    const int chunk = blockIdx.x >> 3;
    const int per = (EE + FCHUNK - 1) / FCHUNK;
    const int e0 = chunk * per;
    int e1 = e0 + per; if (e1 > EE) e1 = EE;
    for (int e = e0 + threadIdx.x; e < e1; e += 256) {
        int d = __builtin_nontemporal_load(&dst[e]);
        if (d >= lo && d < hi) {
            int pos = atomicAdd(&cursor[d], 1);
            csr[rs[d] + pos] = make_int2(__builtin_nontemporal_load(&src[e]),
                                         __float_as_int(__builtin_nontemporal_load(&w[e])));
        }
    }
}

// ---------------- MFMA GEMM: swizzled bf16 A and B, 32-row tile, out row-major bf16 ----------------
__global__ __launch_bounds__(256, 4) void gemm_mfma(const unsigned short* __restrict__ Xs,
                                                    const unsigned short* __restrict__ Mth,
                                                    const unsigned short* __restrict__ Mtl,
                                                    unsigned short* __restrict__ outh,
                                                    int nrows) {
    const int wave = threadIdx.x >> 6;
    const int lane = threadIdx.x & 63;
    const int row0 = blockIdx.x * 32;
    const int col0 = wave * 32;
    const int lr = lane & 15;
    const int kg = lane >> 4;
    const int lastT = nrows / 16 - 1;

    f32x4 acc[2][2];
    #pragma unroll
    for (int m = 0; m < 2; ++m)
        #pragma unroll
        for (int n = 0; n < 2; ++n)
            acc[m][n] = (f32x4){0.f, 0.f, 0.f, 0.f};

    #pragma unroll
    for (int k0 = 0; k0 < 128; k0 += 32) {
        const int kq = (k0 >> 3) + kg;
        s16x8 a[2];
        #pragma unroll
        for (int m = 0; m < 2; ++m) {
            int t = (row0 >> 4) + m;
            if (t > lastT) t = lastT;
            a[m] = *(const s16x8*)(Xs + (size_t)t * 2048 + (size_t)kq * 128 + lr * 8);
        }
        #pragma unroll
        for (int n = 0; n < 2; ++n) {
            const size_t bo = (size_t)((col0 >> 4) + n) * 2048 + (size_t)kq * 128 + lr * 8;
            s16x8 bh = *(const s16x8*)(Mth + bo);
            s16x8 bl = *(const s16x8*)(Mtl + bo);
            #pragma unroll
            for (int m = 0; m < 2; ++m) {
                acc[m][n] = __builtin_amdgcn_mfma_f32_16x16x32_bf16(a[m], bh, acc[m][n], 0, 0, 0);
                acc[m][n] = __builtin_amdgcn_mfma_f32_16x16x32_bf16(a[m], bl, acc[m][n], 0, 0, 0);
            }
        }
    }

    // D layout: col = lane&15, row = (lane>>4)*4 + j   [m89]
    #pragma unroll
    for (int m = 0; m < 2; ++m)
        #pragma unroll
        for (int n = 0; n < 2; ++n)
            #pragma unroll
            for (int j = 0; j < 4; ++j) {
                int r = row0 + m * 16 + kg * 4 + j;
                int c = col0 + n * 16 + lr;
                if (r < nrows)
                    outh[(size_t)r * 128 + c] = f2bf(acc[m][n][j]);
            }
}

// ---------------- dual GEMM: P = bf16( H@W2 + emb@Wm' ), all operands swizzled ----------------
__global__ __launch_bounds__(256, 4) void gemm_pe(const unsigned short* __restrict__ Hs,
                                                  const unsigned short* __restrict__ Es,
                                                  const unsigned short* __restrict__ W2th,
                                                  const unsigned short* __restrict__ W2tl,
                                                  const unsigned short* __restrict__ Wmth,
                                                  const unsigned short* __restrict__ Wmtl,
                                                  unsigned short* __restrict__ P,
                                                  int nrows) {
    const int wave = threadIdx.x >> 6;
    const int lane = threadIdx.x & 63;
    const int row0 = blockIdx.x * 32;
    const int col0 = wave * 32;
    const int lr = lane & 15;
    const int kg = lane >> 4;
    const int lastT = nrows / 16 - 1;

    f32x4 acc[2][2];
    #pragma unroll
    for (int m = 0; m < 2; ++m)
        #pragma unroll
        for (int n = 0; n < 2; ++n)
            acc[m][n] = (f32x4){0.f, 0.f, 0.f, 0.f};

    #pragma unroll
    for (int k0 = 0; k0 < 128; k0 += 32) {
        const int kq = (k0 >> 3) + kg;
        s16x8 ah[2], ae[2];
        #pragma unroll
        for (int m = 0; m < 2; ++m) {
            int t = (row0 >> 4) + m;
            if (t > lastT) t = lastT;
            const size_t ao = (size_t)t * 2048 + (size_t)kq * 128 + lr * 8;
            ah[m] = *(const s16x8*)(Hs + ao);
            ae[m] = *(const s16x8*)(Es + ao);
        }
        #pragma unroll
        for (int n = 0; n < 2; ++n) {
            const size_t bo = (size_t)((col0 >> 4) + n) * 2048 + (size_t)kq * 128 + lr * 8;
            s16x8 b2h = *(const s16x8*)(W2th + bo);
            s16x8 b2l = *(const s16x8*)(W2tl + bo);
            s16x8 bmh = *(const s16x8*)(Wmth + bo);
            s16x8 bml = *(const s16x8*)(Wmtl + bo);
            #pragma unroll
            for (int m = 0; m < 2; ++m) {
                acc[m][n] = __builtin_amdgcn_mfma_f32_16x16x32_bf16(ah[m], b2h, acc[m][n], 0, 0, 0);
                acc[m][n] = __builtin_amdgcn_mfma_f32_16x16x32_bf16(ah[m], b2l, acc[m][n], 0, 0, 0);
                acc[m][n] = __builtin_amdgcn_mfma_f32_16x16x32_bf16(ae[m], bmh, acc[m][n], 0, 0, 0);
                acc[m][n] = __builtin_amdgcn_mfma_f32_16x16x32_bf16(ae[m], bml, acc[m][n], 0, 0, 0);
            }
        }
    }

    #pragma unroll
    for (int m = 0; m < 2; ++m)
        #pragma unroll
        for (int n = 0; n < 2; ++n)
            #pragma unroll
            for (int j = 0; j < 4; ++j) {
                int r = row0 + m * 16 + kg * 4 + j;
                int c = col0 + n * 16 + lr;
                if (r < nrows)
                    P[(size_t)r * 128 + c] = f2bf(acc[m][n][j]);
            }
}

// ---------------- SpMM 1: h = bf16(relu(A @ h1 + b1)); row-major gather, SWIZZLED output ----------------
__global__ __launch_bounds__(256) void spmm_relu(const unsigned short* __restrict__ h,
                                                 const int* __restrict__ rs,
                                                 const int2* __restrict__ csr,
                                                 const float* __restrict__ bias,
                                                 unsigned short* __restrict__ Hs) {
    int node = blockIdx.x * 8 + (threadIdx.x >> 5);
    int lane = threadIdx.x & 31;
    if (node >= NN) return;
    int e = rs[node];
    const int re = rs[node + 1];
    float4 acc = make_float4(0.f, 0.f, 0.f, 0.f);
    for (; e + 3 < re; e += 4) {
        int2 p0 = csr[e];
        int2 p1 = csr[e + 1];
        int2 p2 = csr[e + 2];
        int2 p3 = csr[e + 3];
        ushort4 v0 = *(const ushort4*)(h + (size_t)p0.x * 128 + lane * 4);
        ushort4 v1 = *(const ushort4*)(h + (size_t)p1.x * 128 + lane * 4);
        ushort4 v2 = *(const ushort4*)(h + (size_t)p2.x * 128 + lane * 4);
        ushort4 v3 = *(const ushort4*)(h + (size_t)p3.x * 128 + lane * 4);
        float w0 = __int_as_float(p0.y), w1 = __int_as_float(p1.y);
        float w2 = __int_as_float(p2.y), w3 = __int_as_float(p3.y);
        acc.x += w0 * bf2f(v0.x) + w1 * bf2f(v1.x) + w2 * bf2f(v2.x) + w3 * bf2f(v3.x);
        acc.y += w0 * bf2f(v0.y) + w1 * bf2f(v1.y) + w2 * bf2f(v2.y) + w3 * bf2f(v3.y);
        acc.z += w0 * bf2f(v0.z) + w1 * bf2f(v1.z) + w2 * bf2f(v2.z) + w3 * bf2f(v3.z);
        acc.w += w0 * bf2f(v0.w) + w1 * bf2f(v1.w) + w2 * bf2f(v2.w) + w3 * bf2f(v3.w);
    }
    for (; e < re; ++e) {
        int2 p0 = csr[e];
        float w0 = __int_as_float(p0.y);
        ushort4 v0 = *(const ushort4*)(h + (size_t)p0.x * 128 + lane * 4);
        acc.x += w0 * bf2f(v0.x); acc.y += w0 * bf2f(v0.y);
        acc.z += w0 * bf2f(v0.z); acc.w += w0 * bf2f(v0.w);
    }
    float4 b = ((const float4*)bias)[lane];
    acc.x = fmaxf(acc.x + b.x, 0.f); acc.y = fmaxf(acc.y + b.y, 0.f);
    acc.z = fmaxf(acc.z + b.z, 0.f); acc.w = fmaxf(acc.w + b.w, 0.f);
    ushort4 o;
    o.x = f2bf(acc.x); o.y = f2bf(acc.y); o.z = f2bf(acc.z); o.w = f2bf(acc.w);
    // swizzled store: element (node, k=lane*4..+4)
    size_t so = (size_t)(node >> 4) * 2048 + (size_t)(lane >> 1) * 128
              + (node & 15) * 8 + (lane & 1) * 4;
    *(ushort4*)(Hs + so) = o;
}

// ---------------- final SpMM: out = A@P + b2 (f32 out), row-major gather ----------------
__global__ __launch_bounds__(256) void spmm_final(const unsigned short* __restrict__ P,
                                                  const int* __restrict__ rs,
                                                  const int2* __restrict__ csr,
                                                  const float* __restrict__ b2,
                                                  float* __restrict__ out) {
    int node = blockIdx.x * 8 + (threadIdx.x >> 5);
    int lane = threadIdx.x & 31;
    if (node >= NN) return;
    int e = rs[node];
    const int re = rs[node + 1];
    float4 acc = make_float4(0.f, 0.f, 0.f, 0.f);
    for (; e + 3 < re; e += 4) {
        int2 p0 = csr[e];
        int2 p1 = csr[e + 1];
        int2 p2 = csr[e + 2];
        int2 p3 = csr[e + 3];
        ushort4 v0 = *(const ushort4*)(P + (size_t)p0.x * 128 + lane * 4);
        ushort4 v1 = *(const ushort4*)(P + (size_t)p1.x * 128 + lane * 4);
        ushort4 v2 = *(const ushort4*)(P + (size_t)p2.x * 128 + lane * 4);
        ushort4 v3 = *(const ushort4*)(P + (size_t)p3.x * 128 + lane * 4);
        float w0 = __int_as_float(p0.y), w1 = __int_as_float(p1.y);
        float w2 = __int_as_float(p2.y), w3 = __int_as_float(p3.y);
        acc.x += w0 * bf2f(v0.x) + w1 * bf2f(v1.x) + w2 * bf2f(v2.x) + w3 * bf2f(v3.x);
        acc.y += w0 * bf2f(v0.y) + w1 * bf2f(v1.y) + w2 * bf2f(v2.y) + w3 * bf2f(v3.y);
        acc.z += w0 * bf2f(v0.z) + w1 * bf2f(v1.z) + w2 * bf2f(v2.z) + w3 * bf2f(v3.z);
        acc.w += w0 * bf2f(v0.w) + w1 * bf2f(v1.w) + w2 * bf2f(v2.w) + w3 * bf2f(v3.w);
    }
    for (; e < re; ++e) {
        int2 p0 = csr[e];
        float w0 = __int_as_float(p0.y);
        ushort4 v0 = *(const ushort4*)(P + (size_t)p0.x * 128 + lane * 4);
        acc.x += w0 * bf2f(v0.x); acc.y += w0 * bf2f(v0.y);
        acc.z += w0 * bf2f(v0.z); acc.w += w0 * bf2f(v0.w);
    }
    float4 b = ((const float4*)b2)[lane];
    float4 r;
    r.x = acc.x + b.x; r.y = acc.y + b.y; r.z = acc.z + b.z; r.w = acc.w + b.w;
    ((float4*)(out + (size_t)node * 128))[lane] = r;
}

static inline size_t align_up(size_t x, size_t a) { return (x + a - 1) / a * a; }

extern "C" void kernel_launch(void* const* d_in, const int* in_sizes, int n_in,
                              void* d_out, int out_size, void* d_ws, size_t ws_size,
                              hipStream_t stream) {
    const float* x   = (const float*)d_in[0];
    const int*   esrc = (const int*)d_in[1];
    const int*   edst = (const int*)d_in[2];
    const float* ew  = (const float*)d_in[3];
    const float* W1  = (const float*)d_in[4];
    const float* b1  = (const float*)d_in[5];
    const float* W2  = (const float*)d_in[6];
    const float* b2  = (const float*)d_in[7];
    const float* Fm  = (const float*)d_in[8];
    const float* emb = (const float*)d_in[9];
    float* out = (float*)d_out;

    char* ws = (char*)d_ws;
    size_t off = 0;
    auto alloc = [&](size_t bytes) -> void* {
        void* p = ws + off;
        off = align_up(off + bytes, 256);
        return p;
    };
    unsigned short* B1 = (unsigned short*)alloc((size_t)NN * DD * 2);   // 12.8 MB: h1 (row-major), then P
    unsigned short* XS = (unsigned short*)alloc((size_t)NN * DD * 2);   // 12.8 MB: swizzled x, then swizzled emb
    float* Wmat   = (float*)alloc(128 * 128 * 4);
    int*   counts = (int*)alloc((size_t)NN * 4);
    int*   cursor = (int*)alloc((size_t)NN * 4);
    float* ssq    = (float*)alloc(256);
    int*   rs     = (int*)alloc((size_t)(NN + 1) * 4);
    int*   bsum   = (int*)alloc(64 * 4);
    int2*  csr    = (int2*)alloc((size_t)EE * 8);                       // 4.8 MB
    unsigned short* W1th = (unsigned short*)alloc(128 * 128 * 2);
    unsigned short* W1tl = (unsigned short*)alloc(128 * 128 * 2);
    unsigned short* W2th = (unsigned short*)alloc(128 * 128 * 2);
    unsigned short* W2tl = (unsigned short*)alloc(128 * 128 * 2);
    unsigned short* Wmth = (unsigned short*)alloc(128 * 128 * 2);
    unsigned short* Wmtl = (unsigned short*)alloc(128 * 128 * 2);
    if (off > ws_size) return;

    // H (relu output, swizzled bf16, 12.8 MB) lives in d_out's bytes;
    // dead after gemm_pe reads it, before spmm_final writes out.
    unsigned short* H = (unsigned short*)d_out;

    // zero [counts | cursor | ssq]
    size_t zero_bytes = (size_t)((char*)ssq - (char*)counts) + 256;
    hipMemsetAsync(counts, 0, zero_bytes, stream);

    // projection matrix + weight conversions (kappa folded into Wm split; B swizzled)
    wmat_kernel<<<128, 128, 0, stream>>>(Fm, Wmat, ssq);
    wsplit_kernel<<<64, 256, 0, stream>>>(Wmat, ssq, Wmth, Wmtl);
    convm2_kernel<<<128, 256, 0, stream>>>(W1, W2, W1th, W1tl, W2th, W2tl);

    // CSR build (XCD-sliced)
    const int sgrid = NSLICE * FCHUNK;   // 1536
    hist_kernel<<<sgrid, 256, 0, stream>>>(edst, counts);
    scan_blocks<<<NB_SCAN, SCAN_BLK, 0, stream>>>(counts, rs, bsum);
    scan_add<<<NB_SCAN, SCAN_BLK, 0, stream>>>(rs, bsum);
    fill_kernel<<<sgrid, 256, 0, stream>>>(esrc, edst, ew, rs, cursor, csr);

    const int tile_grid = NN / 16;            // 3125 (exact)
    const int gemm_grid = (NN + 31) / 32;     // 1563
    const int spmm_grid = (NN + 7) / 8;       // 6250

    // xs = swizzle(bf16(x)) -> XS
    conv_swz<<<tile_grid, 256, 0, stream>>>(x, XS);
    // h1 = bf16(x @ W1) -> B1 (row-major, gather-friendly)
    gemm_mfma<<<gemm_grid, 256, 0, stream>>>(XS, W1th, W1tl, B1, NN);
    // es = swizzle(bf16(emb)) -> XS (x swizzle dead after gemm_mfma)
    conv_swz<<<tile_grid, 256, 0, stream>>>(emb, XS);
    // h = relu(A @ h1 + b1) -> H swizzled (in d_out bytes)
    spmm_relu<<<spmm_grid, 256, 0, stream>>>(B1, rs, csr, b1, H);
    // P = bf16(h @ W2 + emb @ Wm') -> B1 (row-major; h1 dead)
    gemm_pe<<<gemm_grid, 256, 0, stream>>>(H, XS, W2th, W2tl, Wmth, Wmtl, B1, NN);
    // out = A @ P + b2
    spmm_final<<<spmm_grid, 256, 0, stream>>>(B1, rs, csr, b2, out);
}